// Round 2
// baseline (260.783 us; speedup 1.0000x reference)
//
#include <hip/hip_runtime.h>

#define B_ 4
#define T_ 2048
#define D_ 1024
#define H_ 16
#define DH_ 64
#define BH_ (B_*H_)   // 64
#define M_ (B_*T_)    // 8192
#define N3_ (3*D_)    // 3072

typedef __attribute__((ext_vector_type(8))) __bf16 bf16x8;
typedef __attribute__((ext_vector_type(4))) float f32x4;
typedef __attribute__((ext_vector_type(8))) unsigned short u16x8;
typedef __attribute__((ext_vector_type(4))) unsigned short u16x4;

__device__ inline void gload_lds16(const void* g, void* l) {
  __builtin_amdgcn_global_load_lds((const __attribute__((address_space(1))) void*)g,
                                   (__attribute__((address_space(3))) void*)l, 16, 0, 0);
}

__device__ inline unsigned short f2bf(float v) {
  __bf16 t = (__bf16)v;
  return *(unsigned short*)&t;
}

// ---------------- cast x: f32 -> bf16, 8 elems/thread ----------------
__global__ void cast_f32_bf16(const float* __restrict__ in, unsigned short* __restrict__ out, int n8) {
  int i = blockIdx.x * blockDim.x + threadIdx.x;
  if (i >= n8) return;
  const float4* p = (const float4*)(in + (size_t)i * 8);
  float4 a = p[0], b = p[1];
  float v[8] = {a.x, a.y, a.z, a.w, b.x, b.y, b.z, b.w};
  u16x8 r;
#pragma unroll
  for (int j = 0; j < 8; ++j) r[j] = f2bf(v[j]);
  *(u16x8*)(out + (size_t)i * 8) = r;
}

// ------------- transpose+cast weights: f32 [K][N] -> bf16 [N][K] -------------
__global__ void transpose_cast_w(const float* __restrict__ w, unsigned short* __restrict__ wt,
                                 int Kdim, int Ndim) {
  __shared__ unsigned short lds[64][72];
  int n0 = blockIdx.x * 64, k0 = blockIdx.y * 64;
  int tid = threadIdx.x;
#pragma unroll
  for (int i = 0; i < 2; ++i) {
    int idx = i * 256 + tid;
    int r = idx >> 3, c8 = idx & 7;
    const float4* src = (const float4*)(w + (size_t)(k0 + r) * Ndim + n0 + c8 * 8);
    float4 a = src[0], b = src[1];
    float v[8] = {a.x, a.y, a.z, a.w, b.x, b.y, b.z, b.w};
#pragma unroll
    for (int j = 0; j < 8; ++j) lds[r][c8 * 8 + j] = f2bf(v[j]);
  }
  __syncthreads();
#pragma unroll
  for (int i = 0; i < 2; ++i) {
    int idx = i * 256 + tid;
    int r = idx >> 3, c8 = idx & 7;   // r = n-local out row, c8 = k chunk
    u16x8 o;
#pragma unroll
    for (int j = 0; j < 8; ++j) o[j] = lds[c8 * 8 + j][r];
    *(u16x8*)(wt + (size_t)(n0 + r) * Kdim + k0 + c8 * 8) = o;
  }
}

// ------------- transpose V: bf16 [bh][T][64] -> [bh][64][T] -------------
__global__ void transpose_v(const unsigned short* __restrict__ v, unsigned short* __restrict__ vt) {
  __shared__ unsigned short lds[64][72];
  int t0 = blockIdx.x * 64;
  int bh = blockIdx.y;
  int tid = threadIdx.x;
#pragma unroll
  for (int i = 0; i < 2; ++i) {
    int idx = i * 256 + tid;
    int r = idx >> 3, c8 = idx & 7;
    u16x8 a = *(const u16x8*)(v + ((size_t)bh * T_ + t0 + r) * 64 + c8 * 8);
#pragma unroll
    for (int j = 0; j < 8; ++j) lds[r][c8 * 8 + j] = a[j];
  }
  __syncthreads();
#pragma unroll
  for (int i = 0; i < 2; ++i) {
    int idx = i * 256 + tid;
    int d = idx >> 3, c8 = idx & 7;
    u16x8 o;
#pragma unroll
    for (int j = 0; j < 8; ++j) o[j] = lds[c8 * 8 + j][d];
    *(u16x8*)(vt + ((size_t)bh * 64 + d) * T_ + t0 + c8 * 8) = o;
  }
}

// ------------- GEMM: C[M][N] = A[M][1024] * BT[N][1024]^T (bf16 in, fp32 acc) -------------
// epi 0: scatter to q/k/v bufs (bf16, q scaled 0.125); epi 1: fp32 out
__global__ __launch_bounds__(256) void gemm_bt(
    const unsigned short* __restrict__ A,
    const unsigned short* __restrict__ BT,
    int epi,
    unsigned short* __restrict__ qb, unsigned short* __restrict__ kb, unsigned short* __restrict__ vb,
    float* __restrict__ outf) {
  __shared__ __align__(16) unsigned short sA[128 * 64];
  __shared__ __align__(16) unsigned short sB[128 * 64];
  const int tid = threadIdx.x;
  const int wave = tid >> 6, lane = tid & 63, g = lane >> 4, c = lane & 15;
  const int wm = wave >> 1, wn = wave & 1;
  const int m0 = blockIdx.x * 128, n0 = blockIdx.y * 128;

  f32x4 acc[4][4] = {};

  for (int ks = 0; ks < 16; ++ks) {
    const int k0 = ks * 64;
#pragma unroll
    for (int i = 0; i < 4; ++i) {
      int idx = i * 256 + tid;
      int r = idx >> 3, s = idx & 7;
      gload_lds16(A + (size_t)(m0 + r) * 1024 + k0 + 8 * (s ^ (r & 7)),
                  (char*)sA + (i * 256 + wave * 64) * 16);
    }
#pragma unroll
    for (int i = 0; i < 4; ++i) {
      int idx = i * 256 + tid;
      int r = idx >> 3, s = idx & 7;
      gload_lds16(BT + (size_t)(n0 + r) * 1024 + k0 + 8 * (s ^ (r & 7)),
                  (char*)sB + (i * 256 + wave * 64) * 16);
    }
    __syncthreads();
#pragma unroll
    for (int kc = 0; kc < 2; ++kc) {
      bf16x8 af[4], bf[4];
#pragma unroll
      for (int mt = 0; mt < 4; ++mt) {
        int r = wm * 64 + mt * 16 + c;
        af[mt] = *(const bf16x8*)((const char*)sA + r * 128 + 16 * ((4 * kc + g) ^ (r & 7)));
      }
#pragma unroll
      for (int nt = 0; nt < 4; ++nt) {
        int r = wn * 64 + nt * 16 + c;
        bf[nt] = *(const bf16x8*)((const char*)sB + r * 128 + 16 * ((4 * kc + g) ^ (r & 7)));
      }
#pragma unroll
      for (int mt = 0; mt < 4; ++mt)
#pragma unroll
        for (int nt = 0; nt < 4; ++nt)
          acc[mt][nt] = __builtin_amdgcn_mfma_f32_16x16x32_bf16(af[mt], bf[nt], acc[mt][nt], 0, 0, 0);
    }
    __syncthreads();
  }

  if (epi == 0) {
    int which = n0 >> 10;  // 0:q 1:k 2:v  (BN=128 divides 1024, so uniform per block)
    int colbase = n0 - (which << 10);
    unsigned short* dst = which == 0 ? qb : (which == 1 ? kb : vb);
    float scale = which == 0 ? 0.125f : 1.0f;  // 1/sqrt(64), exact in bf16
#pragma unroll
    for (int mt = 0; mt < 4; ++mt)
#pragma unroll
      for (int nt = 0; nt < 4; ++nt)
#pragma unroll
        for (int i = 0; i < 4; ++i) {
          int m = m0 + wm * 64 + mt * 16 + g * 4 + i;
          int n = colbase + wn * 64 + nt * 16 + c;
          int b = m >> 11, t = m & 2047;
          int h = n >> 6, d = n & 63;
          dst[(((size_t)(b * H_ + h) * T_ + t) << 6) + d] = f2bf(acc[mt][nt][i] * scale);
        }
  } else {
#pragma unroll
    for (int mt = 0; mt < 4; ++mt)
#pragma unroll
      for (int nt = 0; nt < 4; ++nt)
#pragma unroll
        for (int i = 0; i < 4; ++i) {
          int m = m0 + wm * 64 + mt * 16 + g * 4 + i;
          int n = n0 + wn * 64 + nt * 16 + c;
          outf[(size_t)m * 1024 + n] = acc[mt][nt][i];
        }
  }
}

// ------------- flash attention: 1 block = (bh, 128 q rows), 4 waves x 2 strips of 16 rows -------------
// Double-buffered K/V staging, ONE __syncthreads per k-tile (stage-next then compute-current:
// the barrier's vmcnt(0) drain waits on loads issued one full compute phase earlier).
__global__ __launch_bounds__(256) void attn(
    const unsigned short* __restrict__ qbp,  // [bh][T][64], pre-scaled by 0.125
    const unsigned short* __restrict__ kb,   // [bh][T][64]
    const unsigned short* __restrict__ vt,   // [bh][64][T]
    unsigned short* __restrict__ ao) {       // [M][1024] bf16
  __shared__ __align__(16) unsigned short sK[2][64 * 64];
  __shared__ __align__(16) unsigned short sV[2][64 * 64];   // V^T tile: [d][k]
  __shared__ __align__(16) unsigned short sP[4 * 16 * 72];
  const int tid = threadIdx.x;
  const int wave = tid >> 6, lane = tid & 63, g = lane >> 4, c = lane & 15;
  const int pb = (T_ / 128 - 1) - blockIdx.x;   // heavy blocks dispatch first
  const int bh = blockIdx.y;
  const int kmax = 2 * pb + 1;                  // last k-tile index for this block
  const int q0s[2] = { pb * 128 + wave * 16, pb * 128 + 64 + wave * 16 };

  // Q as B-fragments (lane holds Q[q0+c][kc*32 + g*8 + j])
  bf16x8 qf[2][2];
#pragma unroll
  for (int s = 0; s < 2; ++s)
#pragma unroll
    for (int kc = 0; kc < 2; ++kc)
      qf[s][kc] = *(const bf16x8*)(qbp + ((size_t)bh * T_ + q0s[s] + c) * 64 + kc * 32 + g * 8);

  float m_run[2] = {-INFINITY, -INFINITY}, l_run[2] = {0.0f, 0.0f};
  f32x4 o[2][4] = {};
  unsigned short* sPw = sP + wave * 16 * 72;

  // staging: 4 gload_lds16 per thread per tile (2 for K, 2 for V^T)
  auto stage = [&](int buf, int kt) {
#pragma unroll
    for (int i = 0; i < 2; ++i) {
      int idx = i * 256 + tid;
      int r = idx >> 3, s8 = idx & 7;
      gload_lds16(kb + ((size_t)bh * T_ + kt * 64 + r) * 64 + 8 * (s8 ^ (r & 7)),
                  (char*)sK[buf] + (i * 256 + wave * 64) * 16);
      gload_lds16(vt + ((size_t)bh * 64 + r) * T_ + kt * 64 + 8 * (s8 ^ (r & 7)),
                  (char*)sV[buf] + (i * 256 + wave * 64) * 16);
    }
  };

  stage(0, 0);
  int cur = 0;
  for (int kt = 0; kt <= kmax; ++kt) {
    __syncthreads();                       // drains vmcnt(0): staged tile kt is ready
    if (kt < kmax) stage(cur ^ 1, kt + 1); // overlap next tile's loads with compute
#pragma unroll
    for (int s = 0; s < 2; ++s) {
      const int diag = 2 * pb + s;         // strip's diagonal k-tile (block-uniform)
      if (kt > diag) continue;

      // S^T = K * Q^T : lane holds S[k = 16*mt + 4*g + i][q = c]
      f32x4 st[4] = {};
#pragma unroll
      for (int kc = 0; kc < 2; ++kc)
#pragma unroll
        for (int mt = 0; mt < 4; ++mt) {
          int r = mt * 16 + c;
          bf16x8 kf = *(const bf16x8*)((const char*)sK[cur] + r * 128 + 16 * ((4 * kc + g) ^ (r & 7)));
          st[mt] = __builtin_amdgcn_mfma_f32_16x16x32_bf16(kf, qf[s][kc], st[mt], 0, 0, 0);
        }

      if (kt == diag) {                    // causal mask, diagonal tile only
        int qg = q0s[s] + c;
#pragma unroll
        for (int mt = 0; mt < 4; ++mt)
#pragma unroll
          for (int i = 0; i < 4; ++i) {
            int kg = kt * 64 + mt * 16 + g * 4 + i;
            if (kg > qg) st[mt][i] = -INFINITY;
          }
      }

      // online softmax for row q = c (4 g-lanes hold disjoint k slices)
      float mx = -INFINITY;
#pragma unroll
      for (int mt = 0; mt < 4; ++mt)
#pragma unroll
        for (int i = 0; i < 4; ++i) mx = fmaxf(mx, st[mt][i]);
      mx = fmaxf(mx, __shfl_xor(mx, 16));
      mx = fmaxf(mx, __shfl_xor(mx, 32));
      float m_new = fmaxf(m_run[s], mx);
      float al = __expf(m_run[s] - m_new);
      float ps = 0.0f;
#pragma unroll
      for (int mt = 0; mt < 4; ++mt)
#pragma unroll
        for (int i = 0; i < 4; ++i) {
          float p = __expf(st[mt][i] - m_new);
          st[mt][i] = p;
          ps += p;
        }
      ps += __shfl_xor(ps, 16);
      ps += __shfl_xor(ps, 32);
      l_run[s] = l_run[s] * al + ps;
      m_run[s] = m_new;

      // P -> per-wave LDS, packed 4-wide (ds_write_b64)
#pragma unroll
      for (int mt = 0; mt < 4; ++mt) {
        u16x4 pk;
#pragma unroll
        for (int i = 0; i < 4; ++i) pk[i] = f2bf(st[mt][i]);
        *(u16x4*)((char*)sPw + c * 144 + mt * 32 + g * 8) = pk;
      }

      // rescale O (O rows are q = 4g + i; al lives at lanes with (lane&15) == q)
      float alr[4];
#pragma unroll
      for (int i = 0; i < 4; ++i) alr[i] = __shfl(al, g * 16 + g * 4 + i);
#pragma unroll
      for (int nt = 0; nt < 4; ++nt)
#pragma unroll
        for (int i = 0; i < 4; ++i) o[s][nt][i] *= alr[i];

      // O += P * V  (A = P from LDS, B = V^T rows from sV)
#pragma unroll
      for (int kc = 0; kc < 2; ++kc) {
        bf16x8 pf = *(const bf16x8*)((const char*)sPw + c * 144 + kc * 64 + g * 16);
#pragma unroll
        for (int nt = 0; nt < 4; ++nt) {
          int r = nt * 16 + c;
          bf16x8 vf = *(const bf16x8*)((const char*)sV[cur] + r * 128 + 16 * ((4 * kc + g) ^ (r & 7)));
          o[s][nt] = __builtin_amdgcn_mfma_f32_16x16x32_bf16(pf, vf, o[s][nt], 0, 0, 0);
        }
      }
    }
    cur ^= 1;
  }

  // finalize: divide by l, store bf16 to [b][t][h*64+d]
  int b = bh >> 4, h = bh & 15;
#pragma unroll
  for (int s = 0; s < 2; ++s) {
    float lr[4];
#pragma unroll
    for (int i = 0; i < 4; ++i) lr[i] = __shfl(l_run[s], g * 16 + g * 4 + i);
#pragma unroll
    for (int nt = 0; nt < 4; ++nt)
#pragma unroll
      for (int i = 0; i < 4; ++i) {
        int t = q0s[s] + g * 4 + i;
        int dcol = h * 64 + nt * 16 + c;
        ao[((size_t)(b * T_ + t)) * 1024 + dcol] = f2bf(o[s][nt][i] / lr[i]);
      }
  }
}

extern "C" void kernel_launch(void* const* d_in, const int* in_sizes, int n_in,
                              void* d_out, int out_size, void* d_ws, size_t ws_size,
                              hipStream_t stream) {
  const float* x = (const float*)d_in[0];
  const float* w_qkv = (const float*)d_in[1];
  const float* w_out = (const float*)d_in[2];
  float* out = (float*)d_out;

  char* ws = (char*)d_ws;
  size_t off = 0;
  auto alloc = [&](size_t bytes) {
    char* p = ws + off;
    off += (bytes + 255) & ~(size_t)255;
    return p;
  };
  unsigned short* xb    = (unsigned short*)alloc((size_t)M_ * D_ * 2);
  unsigned short* wqkvT = (unsigned short*)alloc((size_t)N3_ * D_ * 2);
  unsigned short* woutT = (unsigned short*)alloc((size_t)D_ * D_ * 2);
  unsigned short* qbuf  = (unsigned short*)alloc((size_t)BH_ * T_ * 64 * 2);
  unsigned short* kbuf  = (unsigned short*)alloc((size_t)BH_ * T_ * 64 * 2);
  unsigned short* vbuf  = (unsigned short*)alloc((size_t)BH_ * T_ * 64 * 2);
  unsigned short* vtb   = (unsigned short*)alloc((size_t)BH_ * 64 * T_ * 2);
  unsigned short* ao    = xb;  // reuse: xb dead after QKV GEMM

  cast_f32_bf16<<<(M_ * D_ / 8 + 255) / 256, 256, 0, stream>>>(x, xb, M_ * D_ / 8);
  transpose_cast_w<<<dim3(N3_ / 64, D_ / 64), 256, 0, stream>>>(w_qkv, wqkvT, D_, N3_);
  transpose_cast_w<<<dim3(D_ / 64, D_ / 64), 256, 0, stream>>>(w_out, woutT, D_, D_);
  gemm_bt<<<dim3(M_ / 128, N3_ / 128), 256, 0, stream>>>(xb, wqkvT, 0, qbuf, kbuf, vbuf, nullptr);
  transpose_v<<<dim3(T_ / 64, BH_), 256, 0, stream>>>(vbuf, vtb);
  attn<<<dim3(T_ / 128, BH_), 256, 0, stream>>>(qbuf, kbuf, vtb, ao);
  gemm_bt<<<dim3(M_ / 128, D_ / 128), 256, 0, stream>>>(ao, woutT, 1, nullptr, nullptr, nullptr, out);
}

// Round 3
// 221.560 us; speedup vs baseline: 1.1770x; 1.1770x over previous
//
#include <hip/hip_runtime.h>

#define B_ 4
#define T_ 2048
#define D_ 1024
#define H_ 16
#define DH_ 64
#define BH_ (B_*H_)   // 64
#define M_ (B_*T_)    // 8192
#define N3_ (3*D_)    // 3072

typedef __attribute__((ext_vector_type(8))) __bf16 bf16x8;
typedef __attribute__((ext_vector_type(4))) float f32x4;
typedef __attribute__((ext_vector_type(16))) float f32x16;
typedef __attribute__((ext_vector_type(8))) unsigned short u16x8;

__device__ inline void gload_lds16(const void* g, void* l) {
  __builtin_amdgcn_global_load_lds((const __attribute__((address_space(1))) void*)g,
                                   (__attribute__((address_space(3))) void*)l, 16, 0, 0);
}

__device__ inline unsigned short f2bf(float v) {
  __bf16 t = (__bf16)v;
  return *(unsigned short*)&t;
}

__device__ inline unsigned pk2(float lo, float hi2) {
  return (unsigned)f2bf(lo) | ((unsigned)f2bf(hi2) << 16);
}

// Build PV B-fragment (P^T[16k][32q]) for one 16-k chunk from swapped-QK^T scores.
// Lane (l&31)=q holds S rows crow(r,hi)=(r&3)+8*(r>>2)+4*hi. B-frag wants, per lane,
// k = hi*8+j (j=0..7) packed as 4 bf16-pair words; half the words live on the l^32 partner.
template<int BASE>
__device__ inline bf16x8 buildP(const f32x16& S, int hi) {
  unsigned a = pk2(S[BASE+0], S[BASE+1]);
  unsigned b = pk2(S[BASE+2], S[BASE+3]);
  unsigned c = pk2(S[BASE+4], S[BASE+5]);
  unsigned d = pk2(S[BASE+6], S[BASE+7]);
  unsigned sa = __shfl_xor(a, 32), sb = __shfl_xor(b, 32);
  unsigned sc = __shfl_xor(c, 32), sd = __shfl_xor(d, 32);
  union { unsigned u[4]; bf16x8 v; } U;
  U.u[0] = hi ? sc : a;
  U.u[1] = hi ? sd : b;
  U.u[2] = hi ? c : sa;
  U.u[3] = hi ? d : sb;
  return U.v;
}

// ---------------- cast x: f32 -> bf16, 8 elems/thread ----------------
__global__ void cast_f32_bf16(const float* __restrict__ in, unsigned short* __restrict__ out, int n8) {
  int i = blockIdx.x * blockDim.x + threadIdx.x;
  if (i >= n8) return;
  const float4* p = (const float4*)(in + (size_t)i * 8);
  float4 a = p[0], b = p[1];
  float v[8] = {a.x, a.y, a.z, a.w, b.x, b.y, b.z, b.w};
  u16x8 r;
#pragma unroll
  for (int j = 0; j < 8; ++j) r[j] = f2bf(v[j]);
  *(u16x8*)(out + (size_t)i * 8) = r;
}

// ------------- transpose+cast weights: f32 [K][N] -> bf16 [N][K] -------------
__global__ void transpose_cast_w(const float* __restrict__ w, unsigned short* __restrict__ wt,
                                 int Kdim, int Ndim) {
  __shared__ unsigned short lds[64][72];
  int n0 = blockIdx.x * 64, k0 = blockIdx.y * 64;
  int tid = threadIdx.x;
#pragma unroll
  for (int i = 0; i < 2; ++i) {
    int idx = i * 256 + tid;
    int r = idx >> 3, c8 = idx & 7;
    const float4* src = (const float4*)(w + (size_t)(k0 + r) * Ndim + n0 + c8 * 8);
    float4 a = src[0], b = src[1];
    float v[8] = {a.x, a.y, a.z, a.w, b.x, b.y, b.z, b.w};
#pragma unroll
    for (int j = 0; j < 8; ++j) lds[r][c8 * 8 + j] = f2bf(v[j]);
  }
  __syncthreads();
#pragma unroll
  for (int i = 0; i < 2; ++i) {
    int idx = i * 256 + tid;
    int r = idx >> 3, c8 = idx & 7;
    u16x8 o;
#pragma unroll
    for (int j = 0; j < 8; ++j) o[j] = lds[c8 * 8 + j][r];
    *(u16x8*)(wt + (size_t)(n0 + r) * Kdim + k0 + c8 * 8) = o;
  }
}

// ------------- transpose V: bf16 [bh][T][64] -> [bh][64][T] -------------
__global__ void transpose_v(const unsigned short* __restrict__ v, unsigned short* __restrict__ vt) {
  __shared__ unsigned short lds[64][72];
  int t0 = blockIdx.x * 64;
  int bh = blockIdx.y;
  int tid = threadIdx.x;
#pragma unroll
  for (int i = 0; i < 2; ++i) {
    int idx = i * 256 + tid;
    int r = idx >> 3, c8 = idx & 7;
    u16x8 a = *(const u16x8*)(v + ((size_t)bh * T_ + t0 + r) * 64 + c8 * 8);
#pragma unroll
    for (int j = 0; j < 8; ++j) lds[r][c8 * 8 + j] = a[j];
  }
  __syncthreads();
#pragma unroll
  for (int i = 0; i < 2; ++i) {
    int idx = i * 256 + tid;
    int d = idx >> 3, c8 = idx & 7;
    u16x8 o;
#pragma unroll
    for (int j = 0; j < 8; ++j) o[j] = lds[c8 * 8 + j][d];
    *(u16x8*)(vt + ((size_t)bh * 64 + d) * T_ + t0 + c8 * 8) = o;
  }
}

// ------------- GEMM: C[M][N] = A[M][1024] * BT[N][1024]^T (bf16 in, fp32 acc) -------------
__global__ __launch_bounds__(256) void gemm_bt(
    const unsigned short* __restrict__ A,
    const unsigned short* __restrict__ BT,
    int epi,
    unsigned short* __restrict__ qb, unsigned short* __restrict__ kb, unsigned short* __restrict__ vb,
    float* __restrict__ outf) {
  __shared__ __align__(16) unsigned short sA[128 * 64];
  __shared__ __align__(16) unsigned short sB[128 * 64];
  const int tid = threadIdx.x;
  const int wave = tid >> 6, lane = tid & 63, g = lane >> 4, c = lane & 15;
  const int wm = wave >> 1, wn = wave & 1;
  const int m0 = blockIdx.x * 128, n0 = blockIdx.y * 128;

  f32x4 acc[4][4] = {};

  for (int ks = 0; ks < 16; ++ks) {
    const int k0 = ks * 64;
#pragma unroll
    for (int i = 0; i < 4; ++i) {
      int idx = i * 256 + tid;
      int r = idx >> 3, s = idx & 7;
      gload_lds16(A + (size_t)(m0 + r) * 1024 + k0 + 8 * (s ^ (r & 7)),
                  (char*)sA + (i * 256 + wave * 64) * 16);
    }
#pragma unroll
    for (int i = 0; i < 4; ++i) {
      int idx = i * 256 + tid;
      int r = idx >> 3, s = idx & 7;
      gload_lds16(BT + (size_t)(n0 + r) * 1024 + k0 + 8 * (s ^ (r & 7)),
                  (char*)sB + (i * 256 + wave * 64) * 16);
    }
    __syncthreads();
#pragma unroll
    for (int kc = 0; kc < 2; ++kc) {
      bf16x8 af[4], bf[4];
#pragma unroll
      for (int mt = 0; mt < 4; ++mt) {
        int r = wm * 64 + mt * 16 + c;
        af[mt] = *(const bf16x8*)((const char*)sA + r * 128 + 16 * ((4 * kc + g) ^ (r & 7)));
      }
#pragma unroll
      for (int nt = 0; nt < 4; ++nt) {
        int r = wn * 64 + nt * 16 + c;
        bf[nt] = *(const bf16x8*)((const char*)sB + r * 128 + 16 * ((4 * kc + g) ^ (r & 7)));
      }
#pragma unroll
      for (int mt = 0; mt < 4; ++mt)
#pragma unroll
        for (int nt = 0; nt < 4; ++nt)
          acc[mt][nt] = __builtin_amdgcn_mfma_f32_16x16x32_bf16(af[mt], bf[nt], acc[mt][nt], 0, 0, 0);
    }
    __syncthreads();
  }

  if (epi == 0) {
    int which = n0 >> 10;
    int colbase = n0 - (which << 10);
    unsigned short* dst = which == 0 ? qb : (which == 1 ? kb : vb);
    float scale = which == 0 ? 0.125f : 1.0f;
#pragma unroll
    for (int mt = 0; mt < 4; ++mt)
#pragma unroll
      for (int nt = 0; nt < 4; ++nt)
#pragma unroll
        for (int i = 0; i < 4; ++i) {
          int m = m0 + wm * 64 + mt * 16 + g * 4 + i;
          int n = colbase + wn * 64 + nt * 16 + c;
          int b = m >> 11, t = m & 2047;
          int h = n >> 6, d = n & 63;
          dst[(((size_t)(b * H_ + h) * T_ + t) << 6) + d] = f2bf(acc[mt][nt][i] * scale);
        }
  } else {
#pragma unroll
    for (int mt = 0; mt < 4; ++mt)
#pragma unroll
      for (int nt = 0; nt < 4; ++nt)
#pragma unroll
        for (int i = 0; i < 4; ++i) {
          int m = m0 + wm * 64 + mt * 16 + g * 4 + i;
          int n = n0 + wn * 64 + nt * 16 + c;
          outf[(size_t)m * 1024 + n] = acc[mt][nt][i];
        }
  }
}

// ------------- flash attention: 8 waves x 32 q-rows, 32x32 MFMA, in-register softmax -------------
#define PV_STEP(PF, KC)                                                                \
  {                                                                                    \
    bf16x8 pf = (PF);                                                                  \
    int dr0 = q32, dr1 = 32 + q32;                                                     \
    bf16x8 v0 = *(const bf16x8*)(sV + dr0 * 128 + 16 * (((KC)*2 + hi) ^ (dr0 & 7)));   \
    bf16x8 v1 = *(const bf16x8*)(sV + dr1 * 128 + 16 * (((KC)*2 + hi) ^ (dr1 & 7)));   \
    oT0 = __builtin_amdgcn_mfma_f32_32x32x16_bf16(v0, pf, oT0, 0, 0, 0);               \
    oT1 = __builtin_amdgcn_mfma_f32_32x32x16_bf16(v1, pf, oT1, 0, 0, 0);               \
  }

__global__ __launch_bounds__(512) void attn(
    const unsigned short* __restrict__ qbp,  // [bh][T][64], pre-scaled by 0.125
    const unsigned short* __restrict__ kb,   // [bh][T][64]
    const unsigned short* __restrict__ vt,   // [bh][64][T]
    unsigned short* __restrict__ ao) {       // [M][1024] bf16
  __shared__ __align__(16) char pool[36864];  // staging 32KB (2x(K8K+V8K)); epilogue 36KB reuse
  const int tid = threadIdx.x;
  const int wave = tid >> 6, lane = tid & 63;
  const int q32 = lane & 31, hi = lane >> 5;
  const int pb = (T_ / 256 - 1) - blockIdx.x;  // heavy blocks first
  const int bh = blockIdx.y;
  const int q0w = pb * 256 + wave * 32;
  const int kmax = 4 * pb + 3;
  const int dtile = 4 * pb + (wave >> 1);  // this wave's diagonal k-tile

  // Q as B-fragments: lane holds Q[q0w + (l&31)][dhc*16 + hi*8 + j]
  bf16x8 qf[4];
#pragma unroll
  for (int dhc = 0; dhc < 4; ++dhc)
    qf[dhc] = *(const bf16x8*)(qbp + ((size_t)bh * T_ + q0w + q32) * 64 + dhc * 16 + hi * 8);

  f32x16 oT0 = {}, oT1 = {};  // O^T[64d][32q]: col=lane&31=q (lane-local softmax state)
  float m_run = -INFINITY, l_run = 0.0f;

  auto stage = [&](int buf, int kt) {
    int r = tid >> 3, s8 = tid & 7;
    gload_lds16(kb + ((size_t)bh * T_ + kt * 64 + r) * 64 + 8 * (s8 ^ (r & 7)),
                pool + buf * 8192 + tid * 16);
    gload_lds16(vt + ((size_t)bh * 64 + r) * T_ + kt * 64 + 8 * (s8 ^ (r & 7)),
                pool + 16384 + buf * 8192 + tid * 16);
  };

  stage(0, 0);
  int cur = 0;
  for (int kt = 0; kt <= kmax; ++kt) {
    __syncthreads();                          // tile kt staged (barrier drains vmcnt)
    if (kt < kmax) stage(cur ^ 1, kt + 1);    // overlap next tile's loads with compute
    if (kt <= dtile) {
      const char* sK = pool + cur * 8192;
      const char* sV = pool + 16384 + cur * 8192;

      // S^T[64k][32q] = K * Q^T
      f32x16 st0 = {}, st1 = {};
      __builtin_amdgcn_s_setprio(1);
#pragma unroll
      for (int dhc = 0; dhc < 4; ++dhc) {
        int kr0 = q32, kr1 = 32 + q32;
        bf16x8 k0 = *(const bf16x8*)(sK + kr0 * 128 + 16 * ((dhc * 2 + hi) ^ (kr0 & 7)));
        bf16x8 k1 = *(const bf16x8*)(sK + kr1 * 128 + 16 * ((dhc * 2 + hi) ^ (kr1 & 7)));
        st0 = __builtin_amdgcn_mfma_f32_32x32x16_bf16(k0, qf[dhc], st0, 0, 0, 0);
        st1 = __builtin_amdgcn_mfma_f32_32x32x16_bf16(k1, qf[dhc], st1, 0, 0, 0);
      }
      __builtin_amdgcn_s_setprio(0);

      if (kt == dtile) {  // causal mask on diagonal tile
        int qg = q0w + q32;
#pragma unroll
        for (int r = 0; r < 16; ++r) {
          int krow = kt * 64 + (r & 3) + 8 * (r >> 2) + 4 * hi;
          if (krow > qg) st0[r] = -INFINITY;
          if (krow + 32 > qg) st1[r] = -INFINITY;
        }
      }

      // in-register online softmax (lane owns row q = l&31; partner l^32 holds other 32 k's)
      float mx = st0[0];
#pragma unroll
      for (int r = 1; r < 16; ++r) mx = fmaxf(mx, st0[r]);
#pragma unroll
      for (int r = 0; r < 16; ++r) mx = fmaxf(mx, st1[r]);
      mx = fmaxf(mx, __shfl_xor(mx, 32));
      float m_new = fmaxf(m_run, mx);
      float al = __expf(m_run - m_new);
      float ps = 0.0f;
#pragma unroll
      for (int r = 0; r < 16; ++r) { float p = __expf(st0[r] - m_new); st0[r] = p; ps += p; }
#pragma unroll
      for (int r = 0; r < 16; ++r) { float p = __expf(st1[r] - m_new); st1[r] = p; ps += p; }
      ps += __shfl_xor(ps, 32);
      l_run = l_run * al + ps;
      m_run = m_new;
#pragma unroll
      for (int r = 0; r < 16; ++r) { oT0[r] *= al; oT1[r] *= al; }

      // O^T += V^T * P^T
      __builtin_amdgcn_s_setprio(1);
      PV_STEP(buildP<0>(st0, hi), 0)
      PV_STEP(buildP<8>(st0, hi), 1)
      PV_STEP(buildP<0>(st1, hi), 2)
      PV_STEP(buildP<8>(st1, hi), 3)
      __builtin_amdgcn_s_setprio(0);
    }
    cur ^= 1;
  }

  // epilogue: O^T -> per-wave LDS transpose -> coalesced bf16 store to [b][t][h*64+d]
  __syncthreads();
  unsigned short* ep = (unsigned short*)pool + wave * (32 * 72);
  float inv_l = 1.0f / l_run;
#pragma unroll
  for (int r = 0; r < 16; ++r) {
    int d0 = (r & 3) + 8 * (r >> 2) + 4 * hi;
    ep[q32 * 72 + d0]      = f2bf(oT0[r] * inv_l);
    ep[q32 * 72 + 32 + d0] = f2bf(oT1[r] * inv_l);
  }
  __syncthreads();
  {
    int q = lane >> 1, half = lane & 1;
    int t = q0w + q;
    int b = bh >> 4, h = bh & 15;
    const unsigned short* row = ep + q * 72 + half * 32;
    unsigned short* g = ao + ((size_t)(b * T_ + t)) * 1024 + h * 64 + half * 32;
#pragma unroll
    for (int j = 0; j < 4; ++j)
      *(u16x8*)(g + j * 8) = *(const u16x8*)(row + j * 8);
  }
}

extern "C" void kernel_launch(void* const* d_in, const int* in_sizes, int n_in,
                              void* d_out, int out_size, void* d_ws, size_t ws_size,
                              hipStream_t stream) {
  const float* x = (const float*)d_in[0];
  const float* w_qkv = (const float*)d_in[1];
  const float* w_out = (const float*)d_in[2];
  float* out = (float*)d_out;

  char* ws = (char*)d_ws;
  size_t off = 0;
  auto alloc = [&](size_t bytes) {
    char* p = ws + off;
    off += (bytes + 255) & ~(size_t)255;
    return p;
  };
  unsigned short* xb    = (unsigned short*)alloc((size_t)M_ * D_ * 2);
  unsigned short* wqkvT = (unsigned short*)alloc((size_t)N3_ * D_ * 2);
  unsigned short* woutT = (unsigned short*)alloc((size_t)D_ * D_ * 2);
  unsigned short* qbuf  = (unsigned short*)alloc((size_t)BH_ * T_ * 64 * 2);
  unsigned short* kbuf  = (unsigned short*)alloc((size_t)BH_ * T_ * 64 * 2);
  unsigned short* vbuf  = (unsigned short*)alloc((size_t)BH_ * T_ * 64 * 2);
  unsigned short* vtb   = (unsigned short*)alloc((size_t)BH_ * 64 * T_ * 2);
  unsigned short* ao    = xb;  // reuse: xb dead after QKV GEMM

  cast_f32_bf16<<<(M_ * D_ / 8 + 255) / 256, 256, 0, stream>>>(x, xb, M_ * D_ / 8);
  transpose_cast_w<<<dim3(N3_ / 64, D_ / 64), 256, 0, stream>>>(w_qkv, wqkvT, D_, N3_);
  transpose_cast_w<<<dim3(D_ / 64, D_ / 64), 256, 0, stream>>>(w_out, woutT, D_, D_);
  gemm_bt<<<dim3(M_ / 128, N3_ / 128), 256, 0, stream>>>(xb, wqkvT, 0, qbuf, kbuf, vbuf, nullptr);
  transpose_v<<<dim3(T_ / 64, BH_), 256, 0, stream>>>(vbuf, vtb);
  attn<<<dim3(T_ / 256, BH_), 512, 0, stream>>>(qbuf, kbuf, vtb, ao);
  gemm_bt<<<dim3(M_ / 128, D_ / 128), 256, 0, stream>>>(ao, woutT, 1, nullptr, nullptr, nullptr, out);
}